// Round 1
// 311.597 us; speedup vs baseline: 1.0080x; 1.0080x over previous
//
#include <hip/hip_runtime.h>
#include <stdint.h>

typedef unsigned short u16;
typedef __bf16 bf16x8 __attribute__((ext_vector_type(8)));
typedef unsigned short u16x8 __attribute__((ext_vector_type(8)));
typedef u16x8 u16x8_ma __attribute__((may_alias));
typedef unsigned short u16x4 __attribute__((ext_vector_type(4)));
typedef float f32x4 __attribute__((ext_vector_type(4)));

#define DIN   1024
#define DOUT  4096
#define BM    128
#define BN    128
#define BK    64

__device__ __forceinline__ u16 f2bf(float f) {
  unsigned u = __float_as_uint(f);
  u += 0x7fffu + ((u >> 16) & 1u);   // round-to-nearest-even (finite inputs)
  return (u16)(u >> 16);
}
__device__ __forceinline__ bf16x8 ldfrag(const u16* p) {
  union { u16x8 u; bf16x8 b; } cv;
  cv.u = *(const u16x8_ma*)p;
  return cv.b;
}
__device__ __forceinline__ f32x4 mfma16(bf16x8 a, bf16x8 b, f32x4 c) {
  return __builtin_amdgcn_mfma_f32_16x16x32_bf16(a, b, c, 0, 0, 0);
}
__device__ __forceinline__ void gload_lds16(const u16* g, u16* l) {
  __builtin_amdgcn_global_load_lds(
      (const __attribute__((address_space(1))) void*)g,
      (__attribute__((address_space(3))) void*)l, 16, 0, 0);
}
// Wave-local LDS fence: same-wave DS ops execute in issue order; this only
// (a) stops compiler reordering, (b) waits outstanding DS ops. Much cheaper
// than __syncthreads (no inter-wave coupling, no vmcnt drain).
__device__ __forceinline__ void wave_lds_fence() {
  __asm__ __volatile__("s_waitcnt lgkmcnt(0)" ::: "memory");
}

// Single prep dispatch: fp32->bf16 bulk converts (X, Wb) + blueprint weight
// convert/transpose, dispatched on blockIdx ranges (all branches block-uniform).
//   blocks [0,2048):    X  [8192][1024] f32 -> bf16
//   blocks [2048,3072): Wb [4096][1024] f32 -> bf16
//   blocks [3072,3136): W1 [S][C][H] -> W1T [S][H][C]; W2 [S][H][C] -> W2T [S][C][H]
__global__ void prep_all(const float* __restrict__ X, const float* __restrict__ Wb,
                         const float* __restrict__ W1, const float* __restrict__ W2,
                         u16* __restrict__ Xb, u16* __restrict__ Wbb,
                         u16* __restrict__ W1T, u16* __restrict__ W2T) {
  __shared__ u16 tile[8192];
  const int b = blockIdx.x;
  const int t = threadIdx.x;

  if (b < 3072) {
    const float* src; u16* dst; int n4, i, stride;
    if (b < 2048) { src = X;  dst = Xb;  n4 = (8192 * 1024) / 4; i = b * 256 + t;          stride = 2048 * 256; }
    else          { src = Wb; dst = Wbb; n4 = (4096 * 1024) / 4; i = (b - 2048) * 256 + t; stride = 1024 * 256; }
    for (; i < n4; i += stride) {
      f32x4 v = ((const f32x4*)src)[i];
      u16x4 o;
      o.x = f2bf(v.x); o.y = f2bf(v.y); o.z = f2bf(v.z); o.w = f2bf(v.w);
      ((u16x4*)dst)[i] = o;
    }
    return;
  }

  const int s = b - 3072;
  const float* w1 = W1 + s * 8192;
  u16* w1t = W1T + s * 8192;
  for (int i = t; i < 8192; i += 256) tile[i] = f2bf(w1[i]);   // coalesced read
  __syncthreads();
  for (int i = t; i < 8192; i += 256) {                        // coalesced write
    int h = i >> 6, c = i & 63;
    w1t[i] = tile[c * 128 + h];
  }
  __syncthreads();

  const float* w2 = W2 + s * 8192;
  u16* w2t = W2T + s * 8192;
  for (int i = t; i < 8192; i += 256) tile[i] = f2bf(w2[i]);
  __syncthreads();
  for (int i = t; i < 8192; i += 256) {
    int c = i >> 7, h = i & 127;
    w2t[i] = tile[h * 64 + c];
  }
}

// Fused: base = x@Wb^T + bb (128x128 tile, m97 structure + XOR-swizzled LDS),
// then per-wave (one seed per wave column-half) blueprint MLP + alpha blend.
// NOTES:
//  * every acc[] index must be compile-time constant (R3: scratch demotion,
//    2.3 GB HBM write amplification).
//  * LDS tile rows are 128 B: without swizzle a quad's 16 lanes hit the same
//    4 banks on ds_read_b128 (16-way conflict, R4: 2.6e7 conflict cycles).
//    Lane l stages global chunk (l&7)^(row&7); readers XOR chunk with row&7.
//  * inactive seeds (a == 0): out == y EXACTLY -> wave-uniform early-out,
//    skip the entire blueprint MLP (~half the seeds; epilogue nearly halves).
__global__ __launch_bounds__(256, 2) void kasmina_fused(
    const u16* __restrict__ X,   const u16* __restrict__ Wb,   // bf16 (pre-converted)
    const float* __restrict__ bb,  const float* __restrict__ b1,
    const float* __restrict__ b2,  const float* __restrict__ alpha,
    const int* __restrict__ active,
    const u16* __restrict__ W1T, const u16* __restrict__ W2T,  // bf16
    float* __restrict__ out)
{
  // LDS: staging As[128][64] @0, Bs[128][64] @8192. Epilogue reuses it as 4
  // wave-private regions of 4608 el: Ys[32][72] + Hs[32][72] (stride 72).
  __shared__ u16 lds[18432];

  const int t = threadIdx.x;
  const int w = t >> 6, l = t & 63;
  const int wm = w >> 1, wn = w & 1;
  const int lane15 = l & 15, quad = l >> 4;
  const int bn0 = blockIdx.x * BN;
  const int bm0 = blockIdx.y * BM;

  f32x4 acc[4][4];
#pragma unroll
  for (int mt = 0; mt < 4; ++mt)
#pragma unroll
    for (int nt = 0; nt < 4; ++nt)
      acc[mt][nt] = (f32x4){0.f, 0.f, 0.f, 0.f};

  // staging lane map with XOR swizzle: lane l covers row (l>>3) of its 8-row
  // chunk and global 8-col chunk ((l&7)^(row&7)); LDS slot stays base+16*l.
  const int srow = l >> 3;                  // 0..7, == row&7
  const int scol = ((l & 7) ^ srow) << 3;
  const u16* xg = X  + (size_t)(bm0 + srow) * DIN + scol;
  const u16* wg = Wb + (size_t)(bn0 + srow) * DIN + scol;

  // fragment-read swizzle: chunk' = (ks*4+quad) ^ (row&7); row&7 == lane15&7
  const int xr = lane15 & 7;
  const int oswz = (quad ^ xr) << 3;        // u16 offset, ks=0; ks=1: ^32
  const u16* Ab = &lds[(wm * 64 + lane15) * 64];
  const u16* Bb = &lds[8192 + (wn * 64 + lane15) * 64];

  for (int kt = 0; kt < DIN / BK; ++kt) {
    const int k0 = kt * BK;
#pragma unroll
    for (int i = 0; i < 4; ++i) {
      const int q = i * 4 + w;                       // chunk: rows q*8..q*8+7
      gload_lds16(xg + (size_t)(q * 8) * DIN + k0, &lds[q * 512]);
      gload_lds16(wg + (size_t)(q * 8) * DIN + k0, &lds[8192 + q * 512]);
    }
    __syncthreads();
#pragma unroll
    for (int ks = 0; ks < 2; ++ks) {
      const int o = oswz ^ (ks << 5);
      bf16x8 af[4], bfx[4];
#pragma unroll
      for (int mt = 0; mt < 4; ++mt) af[mt] = ldfrag(Ab + mt * 1024 + o);
#pragma unroll
      for (int nt = 0; nt < 4; ++nt) bfx[nt] = ldfrag(Bb + nt * 1024 + o);
#pragma unroll
      for (int mt = 0; mt < 4; ++mt)
#pragma unroll
        for (int nt = 0; nt < 4; ++nt)
          acc[mt][nt] = mfma16(af[mt], bfx[nt], acc[mt][nt]);
    }
    __syncthreads();   // final iter: also releases As/Bs for epilogue reuse
  }

  // ---------------- epilogue: per-seed MLP + blend ----------------
  const int sidx = blockIdx.x * 2 + wn;              // wave's seed
  const int act = active[sidx];                      // wave-uniform
  float bbv[4];
#pragma unroll
  for (int nt = 0; nt < 4; ++nt) bbv[nt] = bb[sidx * 64 + nt * 16 + lane15];

  const size_t orow0 = (size_t)(bm0 + wm * 64);

  if (!act) {
    // a == 0  ->  out = y = base + bb, exactly. Skip the MLP entirely.
#pragma unroll
    for (int mt = 0; mt < 4; ++mt)
#pragma unroll
      for (int nt = 0; nt < 4; ++nt) {
        f32x4 yv = acc[mt][nt];
        const int col = sidx * 64 + nt * 16 + lane15;
#pragma unroll
        for (int r = 0; r < 4; ++r) {
          const size_t row = orow0 + mt * 16 + quad * 4 + r;
          out[row * DOUT + col] = yv[r] + bbv[nt];
        }
      }
    return;   // no block-wide syncs remain; active waves keep their LDS region
  }

  const float aval = alpha[sidx];

  u16* Yw = &lds[w * 4608];        // [32][72] — wave-private
  u16* Hw = Yw + 2304;             // [32][72] — wave-private

#pragma unroll                      // MUST fully unroll: acc[] indices constant
  for (int mh = 0; mh < 2; ++mh) {  // 32-row halves
    // y (=base chunk incl. bias) -> LDS bf16, A-operand [m][c] layout.
#pragma unroll
    for (int mt = 0; mt < 2; ++mt)
#pragma unroll
      for (int nt = 0; nt < 4; ++nt) {
        f32x4 v = acc[mh * 2 + mt][nt];
        const int col = nt * 16 + lane15;
#pragma unroll
        for (int r = 0; r < 4; ++r)
          Yw[(mt * 16 + quad * 4 + r) * 72 + col] = f2bf(v[r] + bbv[nt]);
      }
    wave_lds_fence();              // Yw write -> read (wave-local)

    f32x4 bp[2][4];
#pragma unroll
    for (int nt = 0; nt < 4; ++nt) {
      const float b2v = b2[sidx * 64 + nt * 16 + lane15];
      const f32x4 tv = (f32x4){b2v, b2v, b2v, b2v};
      bp[0][nt] = tv; bp[1][nt] = tv;
    }

#pragma unroll 1
    for (int hh = 0; hh < 2; ++hh) {  // H=128 in two halves of 64
      f32x4 hc[2][4];
#pragma unroll
      for (int nt = 0; nt < 4; ++nt) {
        const float b1v = b1[sidx * 128 + hh * 64 + nt * 16 + lane15];
        const f32x4 tv = (f32x4){b1v, b1v, b1v, b1v};
        hc[0][nt] = tv; hc[1][nt] = tv;
      }
      // GEMM1: h = y @ W1_s   (M=32, N=64(half), K=64)
      const u16* w1b = W1T + sidx * 8192 + (hh * 64 + lane15) * 64 + quad * 8;
#pragma unroll
      for (int ks = 0; ks < 2; ++ks) {
        bf16x8 af0 = ldfrag(Yw + lane15 * 72 + ks * 32 + quad * 8);
        bf16x8 af1 = ldfrag(Yw + (16 + lane15) * 72 + ks * 32 + quad * 8);
#pragma unroll
        for (int nt = 0; nt < 4; ++nt) {
          bf16x8 bfr = ldfrag(w1b + nt * 1024 + ks * 32);   // L2-hot
          hc[0][nt] = mfma16(af0, bfr, hc[0][nt]);
          hc[1][nt] = mfma16(af1, bfr, hc[1][nt]);
        }
      }
      // relu -> bf16 -> Hs
#pragma unroll
      for (int mt = 0; mt < 2; ++mt)
#pragma unroll
        for (int nt = 0; nt < 4; ++nt) {
          f32x4 v = hc[mt][nt];
          const int col = nt * 16 + lane15;
#pragma unroll
          for (int r = 0; r < 4; ++r) {
            float hv = v[r] > 0.f ? v[r] : 0.f;
            Hw[(mt * 16 + quad * 4 + r) * 72 + col] = f2bf(hv);
          }
        }
      wave_lds_fence();            // Hw write -> read (wave-local)
      // GEMM2: bp += h @ W2_s[half]   (M=32, N=64, K=64)
      const u16* w2b = W2T + sidx * 8192 + lane15 * 128 + hh * 64 + quad * 8;
#pragma unroll
      for (int ks = 0; ks < 2; ++ks) {
        bf16x8 af0 = ldfrag(Hw + lane15 * 72 + ks * 32 + quad * 8);
        bf16x8 af1 = ldfrag(Hw + (16 + lane15) * 72 + ks * 32 + quad * 8);
#pragma unroll
        for (int nt = 0; nt < 4; ++nt) {
          bf16x8 bfr = ldfrag(w2b + nt * 2048 + ks * 32);
          bp[0][nt] = mfma16(af0, bfr, bp[0][nt]);
          bp[1][nt] = mfma16(af1, bfr, bp[1][nt]);
        }
      }
      wave_lds_fence();            // Hw read -> next-iter write (WAR)
    }
    // blend (y in fp32 from acc, unquantized) + fp32 store
#pragma unroll
    for (int mt = 0; mt < 2; ++mt)
#pragma unroll
      for (int nt = 0; nt < 4; ++nt) {
        f32x4 yv = acc[mh * 2 + mt][nt];
        f32x4 pv = bp[mt][nt];
        const int col = sidx * 64 + nt * 16 + lane15;
#pragma unroll
        for (int r = 0; r < 4; ++r) {
          const float y = yv[r] + bbv[nt];
          const float o = (1.0f - aval) * y + aval * pv[r];
          const size_t row = orow0 + mh * 32 + mt * 16 + quad * 4 + r;
          out[row * DOUT + col] = o;
        }
      }
    wave_lds_fence();              // Yw/Hw reuse for next half (WAR)
  }
}

extern "C" void kernel_launch(void* const* d_in, const int* in_sizes, int n_in,
                              void* d_out, int out_size, void* d_ws, size_t ws_size,
                              hipStream_t stream) {
  const float* X     = (const float*)d_in[0];   // [8192][1024] fp32
  const float* Wb    = (const float*)d_in[1];   // [4096][1024] fp32
  const float* bbp   = (const float*)d_in[2];   // [4096]
  const float* W1    = (const float*)d_in[3];   // [64][64][128]
  const float* b1p   = (const float*)d_in[4];   // [64][128]
  const float* W2    = (const float*)d_in[5];   // [64][128][64]
  const float* b2p   = (const float*)d_in[6];   // [64][64]
  const float* alpha = (const float*)d_in[7];   // [64]
  const int*  active = (const int*)d_in[8];     // [64]
  float* out = (float*)d_out;

  // workspace layout (u16 units): W1T 512K | W2T 512K | Xb 8.39M | Wbb 4.19M
  u16* W1T = (u16*)d_ws;
  u16* W2T = W1T + 524288;
  u16* Xb  = W1T + 1048576;
  u16* Wbb = W1T + 9437184;       // total ~27.3 MB

  prep_all<<<3136, 256, 0, stream>>>(X, Wb, W1, W2, Xb, Wbb, W1T, W2T);
  kasmina_fused<<<dim3(32, 64), 256, 0, stream>>>(
      Xb, Wbb, bbp, b1p, b2p, alpha, active, W1T, W2T, out);
}

// Round 2
// 302.503 us; speedup vs baseline: 1.0383x; 1.0301x over previous
//
#include <hip/hip_runtime.h>
#include <stdint.h>

typedef unsigned short u16;
typedef __bf16 bf16x8 __attribute__((ext_vector_type(8)));
typedef unsigned short u16x8 __attribute__((ext_vector_type(8)));
typedef u16x8 u16x8_ma __attribute__((may_alias));
typedef unsigned short u16x4 __attribute__((ext_vector_type(4)));
typedef float f32x4 __attribute__((ext_vector_type(4)));

#define DIN   1024
#define DOUT  4096
#define BM    256
#define BN    256
#define BK    64

__device__ __forceinline__ u16 f2bf(float f) {
  unsigned u = __float_as_uint(f);
  u += 0x7fffu + ((u >> 16) & 1u);   // round-to-nearest-even (finite inputs)
  return (u16)(u >> 16);
}
__device__ __forceinline__ bf16x8 ldfrag(const u16* p) {
  union { u16x8 u; bf16x8 b; } cv;
  cv.u = *(const u16x8_ma*)p;
  return cv.b;
}
__device__ __forceinline__ f32x4 mfma16(bf16x8 a, bf16x8 b, f32x4 c) {
  return __builtin_amdgcn_mfma_f32_16x16x32_bf16(a, b, c, 0, 0, 0);
}
__device__ __forceinline__ void gload_lds16(const u16* g, u16* l) {
  __builtin_amdgcn_global_load_lds(
      (const __attribute__((address_space(1))) void*)g,
      (__attribute__((address_space(3))) void*)l, 16, 0, 0);
}
__device__ __forceinline__ void wave_lds_fence() {
  __asm__ __volatile__("s_waitcnt lgkmcnt(0)" ::: "memory");
}

// Single prep dispatch: fp32->bf16 bulk converts (X, Wb) + blueprint weight
// convert/transpose, dispatched on blockIdx ranges (all branches block-uniform).
__global__ void prep_all(const float* __restrict__ X, const float* __restrict__ Wb,
                         const float* __restrict__ W1, const float* __restrict__ W2,
                         u16* __restrict__ Xb, u16* __restrict__ Wbb,
                         u16* __restrict__ W1T, u16* __restrict__ W2T) {
  __shared__ u16 tile[8192];
  const int b = blockIdx.x;
  const int t = threadIdx.x;

  if (b < 3072) {
    const float* src; u16* dst; int n4, i, stride;
    if (b < 2048) { src = X;  dst = Xb;  n4 = (8192 * 1024) / 4; i = b * 256 + t;          stride = 2048 * 256; }
    else          { src = Wb; dst = Wbb; n4 = (4096 * 1024) / 4; i = (b - 2048) * 256 + t; stride = 1024 * 256; }
    for (; i < n4; i += stride) {
      f32x4 v = ((const f32x4*)src)[i];
      u16x4 o;
      o.x = f2bf(v.x); o.y = f2bf(v.y); o.z = f2bf(v.z); o.w = f2bf(v.w);
      ((u16x4*)dst)[i] = o;
    }
    return;
  }

  const int s = b - 3072;
  const float* w1 = W1 + s * 8192;
  u16* w1t = W1T + s * 8192;
  for (int i = t; i < 8192; i += 256) tile[i] = f2bf(w1[i]);
  __syncthreads();
  for (int i = t; i < 8192; i += 256) {
    int h = i >> 6, c = i & 63;
    w1t[i] = tile[c * 128 + h];
  }
  __syncthreads();

  const float* w2 = W2 + s * 8192;
  u16* w2t = W2T + s * 8192;
  for (int i = t; i < 8192; i += 256) tile[i] = f2bf(w2[i]);
  __syncthreads();
  for (int i = t; i < 8192; i += 256) {
    int c = i >> 7, h = i & 127;
    w2t[i] = tile[h * 64 + c];
  }
}

// 256x256-tile 8-phase GEMM (T2 swizzle + T3/T4 counted vmcnt + T5 setprio)
// + fused per-seed blueprint MLP epilogue.
//  * 512 threads = 8 waves (2M x 4N); wave output 128 rows x 64 cols = one seed.
//  * LDS 128 KiB: double-buffered K-tiles (A 256x64 + B 256x64 per buffer).
//  * Per K-tile j: 4 phases; ALL ds_reads of buf[cur] front-loaded in P1/P2
//    (drained via lgkmcnt(0) before P2's barrier) so P3/P4 may prefetch
//    K-tile j+2 into the SAME buffer. Group-end s_waitcnt vmcnt(8) keeps 8
//    loads in flight across barriers (never drains to 0 in steady state).
//  * Raw s_barrier (not __syncthreads) so the compiler doesn't insert a
//    vmcnt(0) drain and defeat the counted pipeline.
//  * XOR swizzle (both sides): lane stages global chunk (l&7)^(row&7) into
//    linear LDS slot; readers XOR chunk with row&7 (bank-conflict-free).
//  * inactive seeds (a==0): out == y exactly -> wave-uniform early-out.
__global__ __launch_bounds__(512, 2) void kasmina_fused(
    const u16* __restrict__ X,   const u16* __restrict__ Wb,   // bf16 (pre-converted)
    const float* __restrict__ bb,  const float* __restrict__ b1,
    const float* __restrict__ b2,  const float* __restrict__ alpha,
    const int* __restrict__ active,
    const u16* __restrict__ W1T, const u16* __restrict__ W2T,  // bf16
    float* __restrict__ out)
{
  // u16 units: buf0: A@0 (16384), B@16384 (16384); buf1: A@32768, B@49152.
  // Epilogue reuses [0, 36864) as 8 wave-private Yw/Hw regions of 4608.
  __shared__ u16 lds[65536];

  const int t = threadIdx.x;
  const int w = t >> 6, l = t & 63;
  const int wm = w >> 2, wn = w & 3;           // 2M x 4N waves
  const int lane15 = l & 15, quad = l >> 4;
  const int bn0 = blockIdx.x * BN;
  const int bm0 = blockIdx.y * BM;

  f32x4 acc[8][4];
#pragma unroll
  for (int mt = 0; mt < 8; ++mt)
#pragma unroll
    for (int nt = 0; nt < 4; ++nt)
      acc[mt][nt] = (f32x4){0.f, 0.f, 0.f, 0.f};

  // ---- staging: each wave stages exactly the regions it reads ----
  // A-half wm (128 rows) shared by 4 waves -> wave stages rows wm*128+wn*32..+31
  // B-quarter wn (64 rows) shared by 2 waves -> rows wn*64+wm*32..+31
  const int srow = l >> 3;                     // 0..7 == row&7 (rows 8-aligned)
  const int scol = ((l & 7) ^ srow) << 3;      // XOR-swizzled source chunk
  const int arow = wm * 128 + wn * 32;
  const int brow = wn * 64 + wm * 32;
  const u16* Ag = X  + (size_t)(bm0 + arow + srow) * DIN + scol;
  const u16* Bg = Wb + (size_t)(bn0 + brow + srow) * DIN + scol;
  u16* Albase = lds + arow * 64;               // + cur*32768
  u16* Blbase = lds + 16384 + brow * 64;       // + cur*32768

  // fragment-read swizzle: slot chunk = (ks*4+quad) ^ (row&7); row&7 == lane15&7
  const int xr = lane15 & 7;
  const int oswz = (quad ^ xr) << 3;           // u16 offset; ks=1: ^32

  // ---- prologue: stage K-tile0 -> buf0, K-tile1 -> buf1 ----
#pragma unroll
  for (int c = 0; c < 4; ++c) {
    gload_lds16(Ag + (size_t)(c * 8) * DIN + 0,  Albase + c * 512);
    gload_lds16(Bg + (size_t)(c * 8) * DIN + 0,  Blbase + c * 512);
  }
#pragma unroll
  for (int c = 0; c < 4; ++c) {
    gload_lds16(Ag + (size_t)(c * 8) * DIN + 64, Albase + 32768 + c * 512);
    gload_lds16(Bg + (size_t)(c * 8) * DIN + 64, Blbase + 32768 + c * 512);
  }
  __asm__ __volatile__("s_waitcnt vmcnt(8)" ::: "memory");   // K-tile0 ready
  __builtin_amdgcn_s_barrier();

  // ---- main loop: 16 K-tiles, 4 phases each ----
#pragma unroll 1
  for (int j = 0; j < 16; ++j) {
    const int cur = j & 1;
    const u16* Ab = lds + cur * 32768 + (wm * 128 + lane15) * 64;
    const u16* Bb = lds + cur * 32768 + 16384 + (wn * 64 + lane15) * 64;

    bf16x8 a0[8], b0[4], a1[8], b1f[4];
    // P1: read all ks=0 fragments (12 ds_read_b128)
#pragma unroll
    for (int mt = 0; mt < 8; ++mt) a0[mt] = ldfrag(Ab + mt * 1024 + oswz);
#pragma unroll
    for (int nt = 0; nt < 4; ++nt) b0[nt] = ldfrag(Bb + nt * 1024 + oswz);
    wave_lds_fence();
    __builtin_amdgcn_s_barrier();
    __builtin_amdgcn_s_setprio(1);
#pragma unroll
    for (int mt = 0; mt < 4; ++mt)
#pragma unroll
      for (int nt = 0; nt < 4; ++nt)
        acc[mt][nt] = mfma16(a0[mt], b0[nt], acc[mt][nt]);
    __builtin_amdgcn_s_setprio(0);
    __builtin_amdgcn_s_barrier();

    // P2: read all ks=1 fragments (12 ds_read_b128); drain before barrier so
    // every wave's reads of buf[cur] are complete before any P3 staging write.
#pragma unroll
    for (int mt = 0; mt < 8; ++mt) a1[mt] = ldfrag(Ab + mt * 1024 + (oswz ^ 32));
#pragma unroll
    for (int nt = 0; nt < 4; ++nt) b1f[nt] = ldfrag(Bb + nt * 1024 + (oswz ^ 32));
    wave_lds_fence();
    __builtin_amdgcn_s_barrier();
    __builtin_amdgcn_s_setprio(1);
#pragma unroll
    for (int mt = 4; mt < 8; ++mt)
#pragma unroll
      for (int nt = 0; nt < 4; ++nt)
        acc[mt][nt] = mfma16(a0[mt], b0[nt], acc[mt][nt]);
    __builtin_amdgcn_s_setprio(0);
    __builtin_amdgcn_s_barrier();

    // P3: prefetch A of K-tile j+2 into buf[cur] (reads of buf[cur] all done)
    if (j < 14) {
      const int k0 = (j + 2) * 64;
#pragma unroll
      for (int c = 0; c < 4; ++c)
        gload_lds16(Ag + (size_t)(c * 8) * DIN + k0, Albase + cur * 32768 + c * 512);
    }
    __builtin_amdgcn_s_barrier();
    __builtin_amdgcn_s_setprio(1);
#pragma unroll
    for (int mt = 0; mt < 4; ++mt)
#pragma unroll
      for (int nt = 0; nt < 4; ++nt)
        acc[mt][nt] = mfma16(a1[mt], b1f[nt], acc[mt][nt]);
    __builtin_amdgcn_s_setprio(0);
    __builtin_amdgcn_s_barrier();

    // P4: prefetch B of K-tile j+2; counted wait for K-tile j+1 (next group)
    if (j < 14) {
      const int k0 = (j + 2) * 64;
#pragma unroll
      for (int c = 0; c < 4; ++c)
        gload_lds16(Bg + (size_t)(c * 8) * DIN + k0, Blbase + cur * 32768 + c * 512);
    }
    if (j < 14)       { __asm__ __volatile__("s_waitcnt vmcnt(8)" ::: "memory"); }
    else if (j == 14) { __asm__ __volatile__("s_waitcnt vmcnt(0)" ::: "memory"); }
    __builtin_amdgcn_s_barrier();
    __builtin_amdgcn_s_setprio(1);
#pragma unroll
    for (int mt = 4; mt < 8; ++mt)
#pragma unroll
      for (int nt = 0; nt < 4; ++nt)
        acc[mt][nt] = mfma16(a1[mt], b1f[nt], acc[mt][nt]);
    __builtin_amdgcn_s_setprio(0);
    __builtin_amdgcn_s_barrier();
  }

  // ---------------- epilogue: per-seed MLP + blend ----------------
  const int sidx = blockIdx.x * 4 + wn;              // wave's seed
  const int act = active[sidx];                      // wave-uniform
  float bbv[4];
#pragma unroll
  for (int nt = 0; nt < 4; ++nt) bbv[nt] = bb[sidx * 64 + nt * 16 + lane15];

  const size_t orow0 = (size_t)(bm0 + wm * 128);

  if (!act) {
    // a == 0  ->  out = y = base + bb, exactly. Skip the MLP entirely.
#pragma unroll
    for (int mt = 0; mt < 8; ++mt)
#pragma unroll
      for (int nt = 0; nt < 4; ++nt) {
        f32x4 yv = acc[mt][nt];
        const int col = sidx * 64 + nt * 16 + lane15;
#pragma unroll
        for (int r = 0; r < 4; ++r) {
          const size_t row = orow0 + mt * 16 + quad * 4 + r;
          out[row * DOUT + col] = yv[r] + bbv[nt];
        }
      }
    return;   // no block-wide syncs remain; active waves keep their LDS region
  }

  const float aval = alpha[sidx];

  u16* Yw = &lds[w * 4608];        // [32][72] — wave-private
  u16* Hw = Yw + 2304;             // [32][72] — wave-private

#pragma unroll                      // MUST fully unroll: acc[] indices constant
  for (int mh = 0; mh < 4; ++mh) {  // 32-row quarters of the wave's 128 rows
    // y (=base chunk incl. bias) -> LDS bf16, A-operand [m][c] layout.
#pragma unroll
    for (int mt = 0; mt < 2; ++mt)
#pragma unroll
      for (int nt = 0; nt < 4; ++nt) {
        f32x4 v = acc[mh * 2 + mt][nt];
        const int col = nt * 16 + lane15;
#pragma unroll
        for (int r = 0; r < 4; ++r)
          Yw[(mt * 16 + quad * 4 + r) * 72 + col] = f2bf(v[r] + bbv[nt]);
      }
    wave_lds_fence();              // Yw write -> read (wave-local)

    f32x4 bp[2][4];
#pragma unroll
    for (int nt = 0; nt < 4; ++nt) {
      const float b2v = b2[sidx * 64 + nt * 16 + lane15];
      const f32x4 tv = (f32x4){b2v, b2v, b2v, b2v};
      bp[0][nt] = tv; bp[1][nt] = tv;
    }

#pragma unroll 1
    for (int hh = 0; hh < 2; ++hh) {  // H=128 in two halves of 64
      f32x4 hc[2][4];
#pragma unroll
      for (int nt = 0; nt < 4; ++nt) {
        const float b1v = b1[sidx * 128 + hh * 64 + nt * 16 + lane15];
        const f32x4 tv = (f32x4){b1v, b1v, b1v, b1v};
        hc[0][nt] = tv; hc[1][nt] = tv;
      }
      // GEMM1: h = y @ W1_s   (M=32, N=64(half), K=64)
      const u16* w1b = W1T + sidx * 8192 + (hh * 64 + lane15) * 64 + quad * 8;
#pragma unroll
      for (int ks = 0; ks < 2; ++ks) {
        bf16x8 af0 = ldfrag(Yw + lane15 * 72 + ks * 32 + quad * 8);
        bf16x8 af1 = ldfrag(Yw + (16 + lane15) * 72 + ks * 32 + quad * 8);
#pragma unroll
        for (int nt = 0; nt < 4; ++nt) {
          bf16x8 bfr = ldfrag(w1b + nt * 1024 + ks * 32);   // L2-hot
          hc[0][nt] = mfma16(af0, bfr, hc[0][nt]);
          hc[1][nt] = mfma16(af1, bfr, hc[1][nt]);
        }
      }
      // relu -> bf16 -> Hs
#pragma unroll
      for (int mt = 0; mt < 2; ++mt)
#pragma unroll
        for (int nt = 0; nt < 4; ++nt) {
          f32x4 v = hc[mt][nt];
          const int col = nt * 16 + lane15;
#pragma unroll
          for (int r = 0; r < 4; ++r) {
            float hv = v[r] > 0.f ? v[r] : 0.f;
            Hw[(mt * 16 + quad * 4 + r) * 72 + col] = f2bf(hv);
          }
        }
      wave_lds_fence();            // Hw write -> read (wave-local)
      // GEMM2: bp += h @ W2_s[half]   (M=32, N=64, K=64)
      const u16* w2b = W2T + sidx * 8192 + lane15 * 128 + hh * 64 + quad * 8;
#pragma unroll
      for (int ks = 0; ks < 2; ++ks) {
        bf16x8 af0 = ldfrag(Hw + lane15 * 72 + ks * 32 + quad * 8);
        bf16x8 af1 = ldfrag(Hw + (16 + lane15) * 72 + ks * 32 + quad * 8);
#pragma unroll
        for (int nt = 0; nt < 4; ++nt) {
          bf16x8 bfr = ldfrag(w2b + nt * 2048 + ks * 32);
          bp[0][nt] = mfma16(af0, bfr, bp[0][nt]);
          bp[1][nt] = mfma16(af1, bfr, bp[1][nt]);
        }
      }
      wave_lds_fence();            // Hw read -> next-iter write (WAR)
    }
    // blend (y in fp32 from acc, unquantized) + fp32 store
#pragma unroll
    for (int mt = 0; mt < 2; ++mt)
#pragma unroll
      for (int nt = 0; nt < 4; ++nt) {
        f32x4 yv = acc[mh * 2 + mt][nt];
        f32x4 pv = bp[mt][nt];
        const int col = sidx * 64 + nt * 16 + lane15;
#pragma unroll
        for (int r = 0; r < 4; ++r) {
          const float y = yv[r] + bbv[nt];
          const float o = (1.0f - aval) * y + aval * pv[r];
          const size_t row = orow0 + mh * 32 + mt * 16 + quad * 4 + r;
          out[row * DOUT + col] = o;
        }
      }
    wave_lds_fence();              // Yw/Hw reuse for next quarter (WAR)
  }
}

extern "C" void kernel_launch(void* const* d_in, const int* in_sizes, int n_in,
                              void* d_out, int out_size, void* d_ws, size_t ws_size,
                              hipStream_t stream) {
  const float* X     = (const float*)d_in[0];   // [8192][1024] fp32
  const float* Wb    = (const float*)d_in[1];   // [4096][1024] fp32
  const float* bbp   = (const float*)d_in[2];   // [4096]
  const float* W1    = (const float*)d_in[3];   // [64][64][128]
  const float* b1p   = (const float*)d_in[4];   // [64][128]
  const float* W2    = (const float*)d_in[5];   // [64][128][64]
  const float* b2p   = (const float*)d_in[6];   // [64][64]
  const float* alpha = (const float*)d_in[7];   // [64]
  const int*  active = (const int*)d_in[8];     // [64]
  float* out = (float*)d_out;

  // workspace layout (u16 units): W1T 512K | W2T 512K | Xb 8.39M | Wbb 4.19M
  u16* W1T = (u16*)d_ws;
  u16* W2T = W1T + 524288;
  u16* Xb  = W1T + 1048576;
  u16* Wbb = W1T + 9437184;       // total ~27.3 MB

  prep_all<<<3136, 256, 0, stream>>>(X, Wb, W1, W2, Xb, Wbb, W1T, W2T);
  kasmina_fused<<<dim3(16, 32), 512, 0, stream>>>(
      Xb, Wbb, bbp, b1p, b2p, alpha, active, W1T, W2T, out);
}

// Round 4
// 297.433 us; speedup vs baseline: 1.0560x; 1.0170x over previous
//
#include <hip/hip_runtime.h>
#include <stdint.h>

typedef unsigned short u16;
typedef __bf16 bf16x8 __attribute__((ext_vector_type(8)));
typedef unsigned short u16x8 __attribute__((ext_vector_type(8)));
typedef u16x8 u16x8_ma __attribute__((may_alias));
typedef unsigned short u16x4 __attribute__((ext_vector_type(4)));
typedef float f32x4 __attribute__((ext_vector_type(4)));

#define DIN   1024
#define DOUT  4096
#define BM    256
#define BN    256
#define BK    32
#define NTILE 32          // DIN / BK
#define BUFSZ 16384       // u16 per buffer: A[256][32] + B[256][32]

__device__ __forceinline__ u16 f2bf(float f) {
  unsigned u = __float_as_uint(f);
  u += 0x7fffu + ((u >> 16) & 1u);   // round-to-nearest-even (finite inputs)
  return (u16)(u >> 16);
}
__device__ __forceinline__ bf16x8 ldfrag(const u16* p) {
  union { u16x8 u; bf16x8 b; } cv;
  cv.u = *(const u16x8_ma*)p;
  return cv.b;
}
__device__ __forceinline__ f32x4 mfma16(bf16x8 a, bf16x8 b, f32x4 c) {
  return __builtin_amdgcn_mfma_f32_16x16x32_bf16(a, b, c, 0, 0, 0);
}
__device__ __forceinline__ void gload_lds16(const u16* g, u16* l) {
  __builtin_amdgcn_global_load_lds(
      (const __attribute__((address_space(1))) void*)g,
      (__attribute__((address_space(3))) void*)l, 16, 0, 0);
}
__device__ __forceinline__ void wave_lds_fence() {
  __asm__ __volatile__("s_waitcnt lgkmcnt(0)" ::: "memory");
}

// Single prep dispatch: fp32->bf16 bulk converts (X, Wb) + blueprint weight
// convert/transpose, dispatched on blockIdx ranges (all branches block-uniform).
__global__ void prep_all(const float* __restrict__ X, const float* __restrict__ Wb,
                         const float* __restrict__ W1, const float* __restrict__ W2,
                         u16* __restrict__ Xb, u16* __restrict__ Wbb,
                         u16* __restrict__ W1T, u16* __restrict__ W2T) {
  __shared__ u16 tile[8192];
  const int b = blockIdx.x;
  const int t = threadIdx.x;

  if (b < 3072) {
    const float* src; u16* dst; int n4, i, stride;
    if (b < 2048) { src = X;  dst = Xb;  n4 = (8192 * 1024) / 4; i = b * 256 + t;          stride = 2048 * 256; }
    else          { src = Wb; dst = Wbb; n4 = (4096 * 1024) / 4; i = (b - 2048) * 256 + t; stride = 1024 * 256; }
    for (; i < n4; i += stride) {
      f32x4 v = ((const f32x4*)src)[i];
      u16x4 o;
      o.x = f2bf(v.x); o.y = f2bf(v.y); o.z = f2bf(v.z); o.w = f2bf(v.w);
      ((u16x4*)dst)[i] = o;
    }
    return;
  }

  const int s = b - 3072;
  const float* w1 = W1 + s * 8192;
  u16* w1t = W1T + s * 8192;
  for (int i = t; i < 8192; i += 256) tile[i] = f2bf(w1[i]);
  __syncthreads();
  for (int i = t; i < 8192; i += 256) {
    int h = i >> 6, c = i & 63;
    w1t[i] = tile[c * 128 + h];
  }
  __syncthreads();

  const float* w2 = W2 + s * 8192;
  u16* w2t = W2T + s * 8192;
  for (int i = t; i < 8192; i += 256) tile[i] = f2bf(w2[i]);
  __syncthreads();
  for (int i = t; i < 8192; i += 256) {
    int c = i >> 7, h = i & 127;
    w2t[i] = tile[h * 64 + c];
  }
}

// 256x256-tile GEMM, m201-faithful schedule: BK=32, 4-buffer rotation,
// 2 phases/tile, each {8|4 ds_read + 2 gload_lds -> barrier -> setprio ->
// 16 MFMA -> setprio -> barrier}, ONE counted vmcnt(8) per tile (3 tiles of
// loads in flight, never drained to 0 until the tail). Fused per-seed MLP
// epilogue (unchanged).
//  * Rotation safety: buf[j&3] holds tile j; it is re-staged (tile j+4)
//    only during tile j+1's phases, i.e. after tile j's closing barrier,
//    by which point every wave's reads of it completed (reads precede each
//    wave's MFMAs which precede that barrier).
//  * Swizzle (BK=32 rows = 64 B = 4 chunks): read chunk' = quad ^
//    ((lane15>>1)&3); stage source col chunk = (l&3) ^ ((l>>3)&3). 64 lanes
//    spread 8-per-4-bank-set -> the 1024 B/wave LDS floor (optimal).
//  * inactive seeds (a==0): out == y exactly -> wave-uniform early-out.
__global__ __launch_bounds__(512, 2) void kasmina_fused(
    const u16* __restrict__ X,   const u16* __restrict__ Wb,   // bf16 (pre-converted)
    const float* __restrict__ bb,  const float* __restrict__ b1,
    const float* __restrict__ b2,  const float* __restrict__ alpha,
    const int* __restrict__ active,
    const u16* __restrict__ W1T, const u16* __restrict__ W2T,  // bf16
    float* __restrict__ out)
{
  // u16 units: 4 buffers of 16384 (A[256][32] @ +0, B[256][32] @ +8192).
  // Epilogue reuses [0, 36864) as 8 wave-private Yw/Hw regions of 4608.
  __shared__ u16 lds[65536];

  const int t = threadIdx.x;
  const int w = t >> 6, l = t & 63;
  const int wm = w >> 2, wn = w & 3;           // 2M x 4N waves
  const int lane15 = l & 15, quad = l >> 4;
  const int bn0 = blockIdx.x * BN;
  const int bm0 = blockIdx.y * BM;

  f32x4 acc[8][4];
#pragma unroll
  for (int mt = 0; mt < 8; ++mt)
#pragma unroll
    for (int nt = 0; nt < 4; ++nt)
      acc[mt][nt] = (f32x4){0.f, 0.f, 0.f, 0.f};

  // ---- staging lane map ----
  // One gload_lds16 per wave covers 16 rows x 32 cols (1 KiB). Lane l ->
  // LDS slot row l>>2, chunk l&3; source col chunk (l&3)^((l>>3)&3) (the
  // inverse of the read swizzle). Wave w covers rows g*128 + w*16 .. +15.
  const int rl = l >> 2;
  const int cs = ((l & 3) ^ ((l >> 3) & 3)) << 3;   // u16 col offset
  const u16* Ag = X  + (size_t)(bm0 + w * 16 + rl) * DIN + cs;  // g=1: +128*DIN
  const u16* Bg = Wb + (size_t)(bn0 + w * 16 + rl) * DIN + cs;

  // ---- fragment-read map ----
  const int swz = (quad ^ ((lane15 >> 1) & 3)) << 3;
  const int aoff = (wm * 128 + lane15) * 32 + swz;          // + mt*512
  const int boff = 8192 + (wn * 64 + lane15) * 32 + swz;    // + nt*512

  // ---- prologue: stage tiles 0,1,2 into buf 0,1,2 ----
#pragma unroll
  for (int tt = 0; tt < 3; ++tt) {
    const int k0 = tt * BK;
    u16* dst = &lds[tt * BUFSZ];
    gload_lds16(Ag + k0,                    dst + w * 512);
    gload_lds16(Ag + (size_t)128 * DIN + k0, dst + 4096 + w * 512);
    gload_lds16(Bg + k0,                    dst + 8192 + w * 512);
    gload_lds16(Bg + (size_t)128 * DIN + k0, dst + 12288 + w * 512);
  }
  __asm__ __volatile__("s_waitcnt vmcnt(8)" ::: "memory");   // tile 0 landed
  __builtin_amdgcn_s_barrier();

  // ---- main loop: 32 K-tiles, 2 phases each ----
#pragma unroll 1
  for (int j = 0; j < NTILE; ++j) {
    const u16* bufp = &lds[(j & 3) * BUFSZ];
    const int stg = (j + 3) & 3;
    const int k0n = (j + 3) * BK;

    bf16x8 bfr[4], afr[4], afr2[4];
    // ---- phase 0: reads (4 B + 4 A), stage A(tile j+3), MFMA m-frags 0..3
#pragma unroll
    for (int nt = 0; nt < 4; ++nt) bfr[nt] = ldfrag(bufp + boff + nt * 512);
#pragma unroll
    for (int mt = 0; mt < 4; ++mt) afr[mt] = ldfrag(bufp + aoff + mt * 512);
    if (j < NTILE - 3) {
      u16* dst = &lds[stg * BUFSZ];
      gload_lds16(Ag + k0n,                     dst + w * 512);
      gload_lds16(Ag + (size_t)128 * DIN + k0n, dst + 4096 + w * 512);
    }
    __builtin_amdgcn_s_barrier();
    __builtin_amdgcn_s_setprio(1);
#pragma unroll
    for (int mt = 0; mt < 4; ++mt)
#pragma unroll
      for (int nt = 0; nt < 4; ++nt)
        acc[mt][nt] = mfma16(afr[mt], bfr[nt], acc[mt][nt]);
    __builtin_amdgcn_s_setprio(0);
    __builtin_amdgcn_s_barrier();

    // ---- phase 1: reads (4 A), stage B(tile j+3), counted vmcnt, MFMA 4..7
#pragma unroll
    for (int mt = 0; mt < 4; ++mt) afr2[mt] = ldfrag(bufp + aoff + (mt + 4) * 512);
    if (j < NTILE - 3) {
      u16* dst = &lds[stg * BUFSZ];
      gload_lds16(Bg + k0n,                     dst + 8192 + w * 512);
      gload_lds16(Bg + (size_t)128 * DIN + k0n, dst + 12288 + w * 512);
    }
    // wait for tile j+1 (4 oldest); keep tiles j+2, j+3 (8) in flight.
    if (j < NTILE - 3)       { __asm__ __volatile__("s_waitcnt vmcnt(8)" ::: "memory"); }
    else if (j == NTILE - 3) { __asm__ __volatile__("s_waitcnt vmcnt(4)" ::: "memory"); }
    else if (j == NTILE - 2) { __asm__ __volatile__("s_waitcnt vmcnt(0)" ::: "memory"); }
    __builtin_amdgcn_s_barrier();
    __builtin_amdgcn_s_setprio(1);
#pragma unroll
    for (int mt = 0; mt < 4; ++mt)
#pragma unroll
      for (int nt = 0; nt < 4; ++nt)
        acc[mt + 4][nt] = mfma16(afr2[mt], bfr[nt], acc[mt + 4][nt]);
    __builtin_amdgcn_s_setprio(0);
    __builtin_amdgcn_s_barrier();
  }

  // ---------------- epilogue: per-seed MLP + blend ----------------
  const int sidx = blockIdx.x * 4 + wn;              // wave's seed
  const int act = active[sidx];                      // wave-uniform
  float bbv[4];
#pragma unroll
  for (int nt = 0; nt < 4; ++nt) bbv[nt] = bb[sidx * 64 + nt * 16 + lane15];

  const size_t orow0 = (size_t)(bm0 + wm * 128);

  if (!act) {
    // a == 0  ->  out = y = base + bb, exactly. Skip the MLP entirely.
#pragma unroll
    for (int mt = 0; mt < 8; ++mt)
#pragma unroll
      for (int nt = 0; nt < 4; ++nt) {
        f32x4 yv = acc[mt][nt];
        const int col = sidx * 64 + nt * 16 + lane15;
#pragma unroll
        for (int r = 0; r < 4; ++r) {
          const size_t row = orow0 + mt * 16 + quad * 4 + r;
          out[row * DOUT + col] = yv[r] + bbv[nt];
        }
      }
    return;   // no block-wide syncs remain; active waves keep their LDS region
  }

  const float aval = alpha[sidx];

  u16* Yw = &lds[w * 4608];        // [32][72] — wave-private
  u16* Hw = Yw + 2304;             // [32][72] — wave-private

#pragma unroll                      // MUST fully unroll: acc[] indices constant
  for (int mh = 0; mh < 4; ++mh) {  // 32-row quarters of the wave's 128 rows
    // y (=base chunk incl. bias) -> LDS bf16, A-operand [m][c] layout.
#pragma unroll
    for (int mt = 0; mt < 2; ++mt)
#pragma unroll
      for (int nt = 0; nt < 4; ++nt) {
        f32x4 v = acc[mh * 2 + mt][nt];
        const int col = nt * 16 + lane15;
#pragma unroll
        for (int r = 0; r < 4; ++r)
          Yw[(mt * 16 + quad * 4 + r) * 72 + col] = f2bf(v[r] + bbv[nt]);
      }
    wave_lds_fence();              // Yw write -> read (wave-local)

    f32x4 bp[2][4];
#pragma unroll
    for (int nt = 0; nt < 4; ++nt) {
      const float b2v = b2[sidx * 64 + nt * 16 + lane15];
      const f32x4 tv = (f32x4){b2v, b2v, b2v, b2v};
      bp[0][nt] = tv; bp[1][nt] = tv;
    }

#pragma unroll 1
    for (int hh = 0; hh < 2; ++hh) {  // H=128 in two halves of 64
      f32x4 hc[2][4];
#pragma unroll
      for (int nt = 0; nt < 4; ++nt) {
        const float b1v = b1[sidx * 128 + hh * 64 + nt * 16 + lane15];
        const f32x4 tv = (f32x4){b1v, b1v, b1v, b1v};
        hc[0][nt] = tv; hc[1][nt] = tv;
      }
      // GEMM1: h = y @ W1_s   (M=32, N=64(half), K=64)
      const u16* w1b = W1T + sidx * 8192 + (hh * 64 + lane15) * 64 + quad * 8;
#pragma unroll
      for (int ks = 0; ks < 2; ++ks) {
        bf16x8 af0 = ldfrag(Yw + lane15 * 72 + ks * 32 + quad * 8);
        bf16x8 af1 = ldfrag(Yw + (16 + lane15) * 72 + ks * 32 + quad * 8);
#pragma unroll
        for (int nt = 0; nt < 4; ++nt) {
          bf16x8 bfr = ldfrag(w1b + nt * 1024 + ks * 32);   // L2-hot
          hc[0][nt] = mfma16(af0, bfr, hc[0][nt]);
          hc[1][nt] = mfma16(af1, bfr, hc[1][nt]);
        }
      }
      // relu -> bf16 -> Hs
#pragma unroll
      for (int mt = 0; mt < 2; ++mt)
#pragma unroll
        for (int nt = 0; nt < 4; ++nt) {
          f32x4 v = hc[mt][nt];
          const int col = nt * 16 + lane15;
#pragma unroll
          for (int r = 0; r < 4; ++r) {
            float hv = v[r] > 0.f ? v[r] : 0.f;
            Hw[(mt * 16 + quad * 4 + r) * 72 + col] = f2bf(hv);
          }
        }
      wave_lds_fence();            // Hw write -> read (wave-local)
      // GEMM2: bp += h @ W2_s[half]   (M=32, N=64, K=64)
      const u16* w2b = W2T + sidx * 8192 + lane15 * 128 + hh * 64 + quad * 8;
#pragma unroll
      for (int ks = 0; ks < 2; ++ks) {
        bf16x8 af0 = ldfrag(Hw + lane15 * 72 + ks * 32 + quad * 8);
        bf16x8 af1 = ldfrag(Hw + (16 + lane15) * 72 + ks * 32 + quad * 8);
#pragma unroll
        for (int nt = 0; nt < 4; ++nt) {
          bf16x8 bfr = ldfrag(w2b + nt * 2048 + ks * 32);
          bp[0][nt] = mfma16(af0, bfr, bp[0][nt]);
          bp[1][nt] = mfma16(af1, bfr, bp[1][nt]);
        }
      }
      wave_lds_fence();            // Hw read -> next-iter write (WAR)
    }
    // blend (y in fp32 from acc, unquantized) + fp32 store
#pragma unroll
    for (int mt = 0; mt < 2; ++mt)
#pragma unroll
      for (int nt = 0; nt < 4; ++nt) {
        f32x4 yv = acc[mh * 2 + mt][nt];
        f32x4 pv = bp[mt][nt];
        const int col = sidx * 64 + nt * 16 + lane15;
#pragma unroll
        for (int r = 0; r < 4; ++r) {
          const float y = yv[r] + bbv[nt];
          const float o = (1.0f - aval) * y + aval * pv[r];
          const size_t row = orow0 + mh * 32 + mt * 16 + quad * 4 + r;
          out[row * DOUT + col] = o;
        }
      }
    wave_lds_fence();              // Yw/Hw reuse for next quarter (WAR)
  }
}

extern "C" void kernel_launch(void* const* d_in, const int* in_sizes, int n_in,
                              void* d_out, int out_size, void* d_ws, size_t ws_size,
                              hipStream_t stream) {
  const float* X     = (const float*)d_in[0];   // [8192][1024] fp32
  const float* Wb    = (const float*)d_in[1];   // [4096][1024] fp32
  const float* bbp   = (const float*)d_in[2];   // [4096]
  const float* W1    = (const float*)d_in[3];   // [64][64][128]
  const float* b1p   = (const float*)d_in[4];   // [64][128]
  const float* W2    = (const float*)d_in[5];   // [64][128][64]
  const float* b2p   = (const float*)d_in[6];   // [64][64]
  const float* alpha = (const float*)d_in[7];   // [64]
  const int*  active = (const int*)d_in[8];     // [64]
  float* out = (float*)d_out;

  // workspace layout (u16 units): W1T 512K | W2T 512K | Xb 8.39M | Wbb 4.19M
  u16* W1T = (u16*)d_ws;
  u16* W2T = W1T + 524288;
  u16* Xb  = W1T + 1048576;
  u16* Wbb = W1T + 9437184;       // total ~27.3 MB

  prep_all<<<3136, 256, 0, stream>>>(X, Wb, W1, W2, Xb, Wbb, W1T, W2T);
  kasmina_fused<<<dim3(16, 32), 512, 0, stream>>>(
      Xb, Wbb, bbp, b1p, b2p, alpha, active, W1T, W2T, out);
}

// Round 5
// 296.269 us; speedup vs baseline: 1.0602x; 1.0039x over previous
//
#include <hip/hip_runtime.h>
#include <stdint.h>

typedef unsigned short u16;
typedef __bf16 bf16x8 __attribute__((ext_vector_type(8)));
typedef unsigned short u16x8 __attribute__((ext_vector_type(8)));
typedef u16x8 u16x8_ma __attribute__((may_alias));
typedef unsigned short u16x4 __attribute__((ext_vector_type(4)));
typedef float f32x4 __attribute__((ext_vector_type(4)));

#define DIN   1024
#define DOUT  4096
#define BM    256
#define BN    256
#define BK    32
#define NTILE 32          // DIN / BK
#define BUFSZ 16384       // u16 per buffer: A[256][32] + B[256][32]

__device__ __forceinline__ u16 f2bf(float f) {
  unsigned u = __float_as_uint(f);
  u += 0x7fffu + ((u >> 16) & 1u);   // round-to-nearest-even (finite inputs)
  return (u16)(u >> 16);
}
__device__ __forceinline__ bf16x8 ldfrag(const u16* p) {
  union { u16x8 u; bf16x8 b; } cv;
  cv.u = *(const u16x8_ma*)p;
  return cv.b;
}
__device__ __forceinline__ f32x4 mfma16(bf16x8 a, bf16x8 b, f32x4 c) {
  return __builtin_amdgcn_mfma_f32_16x16x32_bf16(a, b, c, 0, 0, 0);
}
__device__ __forceinline__ void gload_lds16(const u16* g, u16* l) {
  __builtin_amdgcn_global_load_lds(
      (const __attribute__((address_space(1))) void*)g,
      (__attribute__((address_space(3))) void*)l, 16, 0, 0);
}
__device__ __forceinline__ void wave_lds_fence() {
  __asm__ __volatile__("s_waitcnt lgkmcnt(0)" ::: "memory");
}

// Single prep dispatch: fp32->bf16 bulk converts (X, Wb) + blueprint weight
// convert/transpose, dispatched on blockIdx ranges (all branches block-uniform).
__global__ void prep_all(const float* __restrict__ X, const float* __restrict__ Wb,
                         const float* __restrict__ W1, const float* __restrict__ W2,
                         u16* __restrict__ Xb, u16* __restrict__ Wbb,
                         u16* __restrict__ W1T, u16* __restrict__ W2T) {
  __shared__ u16 tile[8192];
  const int b = blockIdx.x;
  const int t = threadIdx.x;

  if (b < 3072) {
    const float* src; u16* dst; int n4, i, stride;
    if (b < 2048) { src = X;  dst = Xb;  n4 = (8192 * 1024) / 4; i = b * 256 + t;          stride = 2048 * 256; }
    else          { src = Wb; dst = Wbb; n4 = (4096 * 1024) / 4; i = (b - 2048) * 256 + t; stride = 1024 * 256; }
    for (; i < n4; i += stride) {
      f32x4 v = ((const f32x4*)src)[i];
      u16x4 o;
      o.x = f2bf(v.x); o.y = f2bf(v.y); o.z = f2bf(v.z); o.w = f2bf(v.w);
      ((u16x4*)dst)[i] = o;
    }
    return;
  }

  const int s = b - 3072;
  const float* w1 = W1 + s * 8192;
  u16* w1t = W1T + s * 8192;
  for (int i = t; i < 8192; i += 256) tile[i] = f2bf(w1[i]);
  __syncthreads();
  for (int i = t; i < 8192; i += 256) {
    int h = i >> 6, c = i & 63;
    w1t[i] = tile[c * 128 + h];
  }
  __syncthreads();

  const float* w2 = W2 + s * 8192;
  u16* w2t = W2T + s * 8192;
  for (int i = t; i < 8192; i += 256) tile[i] = f2bf(w2[i]);
  __syncthreads();
  for (int i = t; i < 8192; i += 256) {
    int c = i >> 7, h = i & 127;
    w2t[i] = tile[h * 64 + c];
  }
}

// 256x256-tile GEMM with REGISTER-PIPELINED fragment reads:
//   iter j: [vmcnt(4) -> barrier -> 12 ds_reads(tile j+1, into the idle frag
//   set) -> stage(tile j+3) -> 32 MFMA(tile j, from the set read at j-1)]
// ONE barrier + one counted vmcnt per K-tile. The in-loop lgkm wait is free:
// the MFMA operands were read a full iteration earlier, so the compiler's
// auto-waitcnt is lgkmcnt(12) (all 12 newer reads may stay in flight).
// Race-freedom (4-buffer rotation):
//   * reads(t j+1) [post-BAR(j)] drain before MFMAS(t j+1) [iter j+1, which
//     precedes BAR(j+2)]; buf[(j+1)&3] is re-staged only at iter j+2
//     [post-BAR(j+2)]  -> read-before-write ordered by BAR(j+2).
//   * stage(t j+3) [post-BAR(j)] overwrites buf[(j-1)&3], whose readers
//     drained before MFMAS(t j-1) [iter j-1, pre-BAR(j)]  -> ordered.
//   * vmcnt(4) before BAR(j): every wave's t(j+1) loads landed before any
//     wave's post-barrier ds_reads of t(j+1).
// Swizzle / fragment maps / epilogue identical to the verified R4 kernel.
// Output stores are non-temporal: the 134 MB write stream otherwise evicts
// the X/Wb panels from L3 (FETCH 76 MB vs ~28 MB ideal).
__global__ __launch_bounds__(512, 2) void kasmina_fused(
    const u16* __restrict__ X,   const u16* __restrict__ Wb,   // bf16 (pre-converted)
    const float* __restrict__ bb,  const float* __restrict__ b1,
    const float* __restrict__ b2,  const float* __restrict__ alpha,
    const int* __restrict__ active,
    const u16* __restrict__ W1T, const u16* __restrict__ W2T,  // bf16
    float* __restrict__ out)
{
  // u16 units: 4 buffers of 16384 (A[256][32] @ +0, B[256][32] @ +8192).
  // Epilogue reuses [0, 36864) as 8 wave-private Yw/Hw regions of 4608.
  __shared__ u16 lds[65536];

  const int t = threadIdx.x;
  const int w = t >> 6, l = t & 63;
  const int wm = w >> 2, wn = w & 3;           // 2M x 4N waves
  const int lane15 = l & 15, quad = l >> 4;
  const int bn0 = blockIdx.x * BN;
  const int bm0 = blockIdx.y * BM;

  f32x4 acc[8][4];
#pragma unroll
  for (int mt = 0; mt < 8; ++mt)
#pragma unroll
    for (int nt = 0; nt < 4; ++nt)
      acc[mt][nt] = (f32x4){0.f, 0.f, 0.f, 0.f};

  // ---- staging lane map (identical to R4) ----
  const int rl = l >> 2;
  const int cs = ((l & 3) ^ ((l >> 3) & 3)) << 3;   // u16 col offset
  const u16* Ag = X  + (size_t)(bm0 + w * 16 + rl) * DIN + cs;
  const u16* Bg = Wb + (size_t)(bn0 + w * 16 + rl) * DIN + cs;

  // ---- fragment-read map (identical to R4) ----
  const int swz = (quad ^ ((lane15 >> 1) & 3)) << 3;
  const int aoff = (wm * 128 + lane15) * 32 + swz;          // + mt*512
  const int boff = 8192 + (wn * 64 + lane15) * 32 + swz;    // + nt*512

#define VM4 __asm__ __volatile__("s_waitcnt vmcnt(4)" ::: "memory")
#define VM0 __asm__ __volatile__("s_waitcnt vmcnt(0)" ::: "memory")
#define VM8 __asm__ __volatile__("s_waitcnt vmcnt(8)" ::: "memory")

#define STAGE(JP3) do {                                                  \
    const int kk_ = (JP3) * BK;                                          \
    u16* dst_ = &lds[((JP3) & 3) * BUFSZ];                               \
    gload_lds16(Ag + kk_,          dst_ +         w * 512);              \
    gload_lds16(Ag + 131072 + kk_, dst_ +  4096 + w * 512);              \
    gload_lds16(Bg + kk_,          dst_ +  8192 + w * 512);              \
    gload_lds16(Bg + 131072 + kk_, dst_ + 12288 + w * 512);              \
  } while (0)

#define READS(AF, BF, BI) do {                                           \
    const u16* bufp_ = &lds[(BI) * BUFSZ];                               \
    _Pragma("unroll")                                                    \
    for (int nt_ = 0; nt_ < 4; ++nt_) BF[nt_] = ldfrag(bufp_ + boff + nt_ * 512); \
    _Pragma("unroll")                                                    \
    for (int mt_ = 0; mt_ < 8; ++mt_) AF[mt_] = ldfrag(bufp_ + aoff + mt_ * 512); \
  } while (0)

#define MFMAS(AF, BF) do {                                               \
    __builtin_amdgcn_s_setprio(1);                                       \
    _Pragma("unroll")                                                    \
    for (int mt_ = 0; mt_ < 8; ++mt_)                                    \
      _Pragma("unroll")                                                  \
      for (int nt_ = 0; nt_ < 4; ++nt_)                                  \
        acc[mt_][nt_] = mfma16(AF[mt_], BF[nt_], acc[mt_][nt_]);         \
    __builtin_amdgcn_s_setprio(0);                                       \
  } while (0)

  bf16x8 afA[8], bfA[4], afB[8], bfB[4];

  // ---- prologue: stage tiles 0,1,2; read tile0 fragments into set A ----
  STAGE(0); STAGE(1); STAGE(2);
  VM8;                                 // tile 0 landed (8 newer stay in flight)
  __builtin_amdgcn_s_barrier();
  READS(afA, bfA, 0);

  // ---- main loop: 2 tiles/iteration, register-pipelined reads ----
#pragma unroll 1
  for (int jb = 0; jb < 30; jb += 2) {
    // iter j = jb: compute set A (tile jb), read set B (tile jb+1)
    VM4;                               // tile jb+1 landed (tile jb+2 in flight)
    __builtin_amdgcn_s_barrier();
    READS(afB, bfB, (jb + 1) & 3);
    STAGE(jb + 3);
    MFMAS(afA, bfA);

    // iter j = jb+1: compute set B (tile jb+1), read set A (tile jb+2)
    VM4;                               // tile jb+2 landed
    __builtin_amdgcn_s_barrier();
    READS(afA, bfA, (jb + 2) & 3);
    if (jb < 28) STAGE(jb + 4);        // stages t5..t31; skip at jb=28
    MFMAS(afB, bfB);
  }
  // j = 30: compute A (tile 30), read B (tile 31)
  VM0;                                 // last loads (tile 31) landed
  __builtin_amdgcn_s_barrier();
  READS(afB, bfB, 3);
  MFMAS(afA, bfA);
  // j = 31: compute B (tile 31)
  MFMAS(afB, bfB);

  __builtin_amdgcn_s_barrier();        // formal fence before LDS reuse

  // ---------------- epilogue: per-seed MLP + blend ----------------
  const int sidx = blockIdx.x * 4 + wn;              // wave's seed
  const int act = active[sidx];                      // wave-uniform
  float bbv[4];
#pragma unroll
  for (int nt = 0; nt < 4; ++nt) bbv[nt] = bb[sidx * 64 + nt * 16 + lane15];

  const size_t orow0 = (size_t)(bm0 + wm * 128);

  if (!act) {
    // a == 0  ->  out = y = base + bb, exactly. Skip the MLP entirely.
#pragma unroll
    for (int mt = 0; mt < 8; ++mt)
#pragma unroll
      for (int nt = 0; nt < 4; ++nt) {
        f32x4 yv = acc[mt][nt];
        const int col = sidx * 64 + nt * 16 + lane15;
#pragma unroll
        for (int r = 0; r < 4; ++r) {
          const size_t row = orow0 + mt * 16 + quad * 4 + r;
          __builtin_nontemporal_store(yv[r] + bbv[nt], &out[row * DOUT + col]);
        }
      }
    return;   // no block-wide syncs remain; active waves keep their LDS region
  }

  const float aval = alpha[sidx];

  u16* Yw = &lds[w * 4608];        // [32][72] — wave-private
  u16* Hw = Yw + 2304;             // [32][72] — wave-private

#pragma unroll                      // MUST fully unroll: acc[] indices constant
  for (int mh = 0; mh < 4; ++mh) {  // 32-row quarters of the wave's 128 rows
    // y (=base chunk incl. bias) -> LDS bf16, A-operand [m][c] layout.
#pragma unroll
    for (int mt = 0; mt < 2; ++mt)
#pragma unroll
      for (int nt = 0; nt < 4; ++nt) {
        f32x4 v = acc[mh * 2 + mt][nt];
        const int col = nt * 16 + lane15;
#pragma unroll
        for (int r = 0; r < 4; ++r)
          Yw[(mt * 16 + quad * 4 + r) * 72 + col] = f2bf(v[r] + bbv[nt]);
      }
    wave_lds_fence();              // Yw write -> read (wave-local)

    f32x4 bp[2][4];
#pragma unroll
    for (int nt = 0; nt < 4; ++nt) {
      const float b2v = b2[sidx * 64 + nt * 16 + lane15];
      const f32x4 tv = (f32x4){b2v, b2v, b2v, b2v};
      bp[0][nt] = tv; bp[1][nt] = tv;
    }

#pragma unroll 1
    for (int hh = 0; hh < 2; ++hh) {  // H=128 in two halves of 64
      f32x4 hc[2][4];
#pragma unroll
      for (int nt = 0; nt < 4; ++nt) {
        const float b1v = b1[sidx * 128 + hh * 64 + nt * 16 + lane15];
        const f32x4 tv = (f32x4){b1v, b1v, b1v, b1v};
        hc[0][nt] = tv; hc[1][nt] = tv;
      }
      // GEMM1: h = y @ W1_s   (M=32, N=64(half), K=64)
      const u16* w1b = W1T + sidx * 8192 + (hh * 64 + lane15) * 64 + quad * 8;
#pragma unroll
      for (int ks = 0; ks < 2; ++ks) {
        bf16x8 af0 = ldfrag(Yw + lane15 * 72 + ks * 32 + quad * 8);
        bf16x8 af1 = ldfrag(Yw + (16 + lane15) * 72 + ks * 32 + quad * 8);
#pragma unroll
        for (int nt = 0; nt < 4; ++nt) {
          bf16x8 bfr = ldfrag(w1b + nt * 1024 + ks * 32);   // L2-hot
          hc[0][nt] = mfma16(af0, bfr, hc[0][nt]);
          hc[1][nt] = mfma16(af1, bfr, hc[1][nt]);
        }
      }
      // relu -> bf16 -> Hs
#pragma unroll
      for (int mt = 0; mt < 2; ++mt)
#pragma unroll
        for (int nt = 0; nt < 4; ++nt) {
          f32x4 v = hc[mt][nt];
          const int col = nt * 16 + lane15;
#pragma unroll
          for (int r = 0; r < 4; ++r) {
            float hv = v[r] > 0.f ? v[r] : 0.f;
            Hw[(mt * 16 + quad * 4 + r) * 72 + col] = f2bf(hv);
          }
        }
      wave_lds_fence();            // Hw write -> read (wave-local)
      // GEMM2: bp += h @ W2_s[half]   (M=32, N=64, K=64)
      const u16* w2b = W2T + sidx * 8192 + lane15 * 128 + hh * 64 + quad * 8;
#pragma unroll
      for (int ks = 0; ks < 2; ++ks) {
        bf16x8 af0 = ldfrag(Hw + lane15 * 72 + ks * 32 + quad * 8);
        bf16x8 af1 = ldfrag(Hw + (16 + lane15) * 72 + ks * 32 + quad * 8);
#pragma unroll
        for (int nt = 0; nt < 4; ++nt) {
          bf16x8 bfr = ldfrag(w2b + nt * 2048 + ks * 32);
          bp[0][nt] = mfma16(af0, bfr, bp[0][nt]);
          bp[1][nt] = mfma16(af1, bfr, bp[1][nt]);
        }
      }
      wave_lds_fence();            // Hw read -> next-iter write (WAR)
    }
    // blend (y in fp32 from acc, unquantized) + fp32 store
#pragma unroll
    for (int mt = 0; mt < 2; ++mt)
#pragma unroll
      for (int nt = 0; nt < 4; ++nt) {
        f32x4 yv = acc[mh * 2 + mt][nt];
        f32x4 pv = bp[mt][nt];
        const int col = sidx * 64 + nt * 16 + lane15;
#pragma unroll
        for (int r = 0; r < 4; ++r) {
          const float y = yv[r] + bbv[nt];
          const float o = (1.0f - aval) * y + aval * pv[r];
          const size_t row = orow0 + mh * 32 + mt * 16 + quad * 4 + r;
          __builtin_nontemporal_store(o, &out[row * DOUT + col]);
        }
      }
    wave_lds_fence();              // Yw/Hw reuse for next quarter (WAR)
  }
}

extern "C" void kernel_launch(void* const* d_in, const int* in_sizes, int n_in,
                              void* d_out, int out_size, void* d_ws, size_t ws_size,
                              hipStream_t stream) {
  const float* X     = (const float*)d_in[0];   // [8192][1024] fp32
  const float* Wb    = (const float*)d_in[1];   // [4096][1024] fp32
  const float* bbp   = (const float*)d_in[2];   // [4096]
  const float* b1p   = (const float*)d_in[4];   // [64][128]
  const float* W1    = (const float*)d_in[3];   // [64][64][128]
  const float* W2    = (const float*)d_in[5];   // [64][128][64]
  const float* b2p   = (const float*)d_in[6];   // [64][64]
  const float* alpha = (const float*)d_in[7];   // [64]
  const int*  active = (const int*)d_in[8];     // [64]
  float* out = (float*)d_out;

  // workspace layout (u16 units): W1T 512K | W2T 512K | Xb 8.39M | Wbb 4.19M
  u16* W1T = (u16*)d_ws;
  u16* W2T = W1T + 524288;
  u16* Xb  = W1T + 1048576;
  u16* Wbb = W1T + 9437184;       // total ~27.3 MB

  prep_all<<<3136, 256, 0, stream>>>(X, Wb, W1, W2, Xb, Wbb, W1T, W2T);
  kasmina_fused<<<dim3(16, 32), 512, 0, stream>>>(
      Xb, Wbb, bbp, b1p, b2p, alpha, active, W1T, W2T, out);
}